// Round 1
// baseline (464.128 us; speedup 1.0000x reference)
//
#include <hip/hip_runtime.h>
#include <hip/hip_bf16.h>

#define WIN 11
#define PAD 5
#define TW 32
#define TH 32
#define IW (TW + 2 * PAD)   // 42
#define IH (TH + 2 * PAD)   // 42
#define LSTR 43             // padded stride for input tiles
#define HSTR 33             // padded stride for horizontal-pass intermediates
#define IMG_H 512
#define IMG_W 512

__global__ __launch_bounds__(64) void ssim_zero(double* ws) {
    if (threadIdx.x == 0) *ws = 0.0;
}

__global__ __launch_bounds__(256) void ssim_main(const float* __restrict__ img1,
                                                 const float* __restrict__ img2,
                                                 double* __restrict__ ws) {
    __shared__ float lx[IH * LSTR];
    __shared__ float ly[IH * LSTR];
    __shared__ float hbuf[5][IH * HSTR];
    __shared__ float wsum[4];

    const int tid = threadIdx.x;
    const int tx0 = blockIdx.x * TW;
    const int ty0 = blockIdx.y * TH;
    const size_t base = (size_t)blockIdx.z * (size_t)(IMG_H * IMG_W);

    // Gaussian weights (match jnp: exp(-d^2/(2*1.5^2)) normalized, f32)
    float g[WIN];
    {
        float s = 0.f;
#pragma unroll
        for (int i = 0; i < WIN; ++i) {
            float d = (float)(i - PAD);
            g[i] = expf(-d * d / 4.5f);
            s += g[i];
        }
        float inv = 1.f / s;
#pragma unroll
        for (int i = 0; i < WIN; ++i) g[i] *= inv;
    }

    // ---- load 42x42 zero-padded tiles of both images into LDS ----
    for (int idx = tid; idx < IH * IW; idx += 256) {
        int r = idx / IW, c = idx - r * IW;
        int gr = ty0 + r - PAD, gc = tx0 + c - PAD;
        float a = 0.f, b = 0.f;
        if (gr >= 0 && gr < IMG_H && gc >= 0 && gc < IMG_W) {
            size_t off = base + (size_t)gr * IMG_W + (size_t)gc;
            a = img1[off];
            b = img2[off];
        }
        lx[r * LSTR + c] = a;
        ly[r * LSTR + c] = b;
    }
    __syncthreads();

    // ---- horizontal 11-tap pass over 5 fused quantities ----
    for (int idx = tid; idx < IH * TW; idx += 256) {
        int r = idx >> 5, c = idx & (TW - 1);
        const float* px = &lx[r * LSTR + c];
        const float* py = &ly[r * LSTR + c];
        float sx = 0.f, sy = 0.f, sxx = 0.f, syy = 0.f, sxy = 0.f;
#pragma unroll
        for (int j = 0; j < WIN; ++j) {
            float w = g[j];
            float a = px[j], b = py[j];
            float wa = w * a, wb = w * b;
            sx += wa;
            sy += wb;
            sxx = fmaf(wa, a, sxx);
            syy = fmaf(wb, b, syy);
            sxy = fmaf(wa, b, sxy);
        }
        int o = r * HSTR + c;
        hbuf[0][o] = sx;
        hbuf[1][o] = sy;
        hbuf[2][o] = sxx;
        hbuf[3][o] = syy;
        hbuf[4][o] = sxy;
    }
    __syncthreads();

    // ---- vertical 11-tap pass + SSIM map + local accumulate ----
    const float C2v = 0.0009f;  // (0.03 * 1.0)^2
    float acc = 0.f;
#pragma unroll
    for (int it = 0; it < (TH * TW) / 256; ++it) {
        int idx = tid + it * 256;
        int r = idx >> 5, c = idx & (TW - 1);
        float sx = 0.f, sy = 0.f, sxx = 0.f, syy = 0.f, sxy = 0.f;
#pragma unroll
        for (int i = 0; i < WIN; ++i) {
            float w = g[i];
            int o = (r + i) * HSTR + c;
            sx  = fmaf(w, hbuf[0][o], sx);
            sy  = fmaf(w, hbuf[1][o], sy);
            sxx = fmaf(w, hbuf[2][o], sxx);
            syy = fmaf(w, hbuf[3][o], syy);
            sxy = fmaf(w, hbuf[4][o], sxy);
        }
        float mu12 = sx * sy;
        float s1 = sxx - sx * sx;
        float s2 = syy - sy * sy;
        float s12 = sxy - mu12;
        float sig = sqrtf(fabsf(s1)) * sqrtf(fabsf(s2));
        acc += (s12 + C2v) / (sig + C2v);
    }

    // ---- block reduction: wave shuffle, then cross-wave via LDS ----
#pragma unroll
    for (int off = 32; off > 0; off >>= 1) acc += __shfl_down(acc, off, 64);
    int wave = tid >> 6;
    if ((tid & 63) == 0) wsum[wave] = acc;
    __syncthreads();
    if (tid == 0) {
        float b = wsum[0] + wsum[1] + wsum[2] + wsum[3];
        atomicAdd(ws, (double)b);  // double accumulator: avoids f32 drift over 24576 adds
    }
}

__global__ __launch_bounds__(64) void ssim_final(const double* __restrict__ ws,
                                                 float* __restrict__ out,
                                                 double inv_total) {
    if (threadIdx.x == 0) out[0] = (float)(ws[0] * inv_total);
}

extern "C" void kernel_launch(void* const* d_in, const int* in_sizes, int n_in,
                              void* d_out, int out_size, void* d_ws, size_t ws_size,
                              hipStream_t stream) {
    const float* img1 = (const float*)d_in[0];
    const float* img2 = (const float*)d_in[1];
    float* out = (float*)d_out;
    double* ws = (double*)d_ws;

    const int total = in_sizes[0];                  // 32*3*512*512
    const int nc = total / (IMG_H * IMG_W);         // 96 images of 512x512

    ssim_zero<<<1, 64, 0, stream>>>(ws);
    dim3 grid(IMG_W / TW, IMG_H / TH, nc);
    ssim_main<<<grid, 256, 0, stream>>>(img1, img2, ws);
    ssim_final<<<1, 64, 0, stream>>>(ws, out, 1.0 / (double)total);
}

// Round 2
// 364.881 us; speedup vs baseline: 1.2720x; 1.2720x over previous
//
#include <hip/hip_runtime.h>
#include <hip/hip_bf16.h>

#define WIN 11
#define PAD 5
#define TW 32
#define TH 32
#define IH 42            // TH + 2*PAD staged rows
#define ISTR 48          // input LDS row stride (floats); LDS col 0 == global col tx0-8
#define HSTR 33          // h-pass row stride (in float4 units / floats)
#define IMG_H 512
#define IMG_W 512

// ---------------- main fused SSIM kernel ----------------
__global__ __launch_bounds__(256) void ssim_main(const float* __restrict__ img1,
                                                 const float* __restrict__ img2,
                                                 float* __restrict__ partial) {
    __shared__ float  lx[IH * ISTR];          // 8064 B
    __shared__ float  ly[IH * ISTR];          // 8064 B
    __shared__ float4 h4[IH * HSTR];          // 22176 B : (sx, sy, sxx, syy)
    __shared__ float  h1[IH * HSTR];          // 5544 B  : sxy
    __shared__ float  wsum[4];

    const int tid = threadIdx.x;
    const int tx0 = blockIdx.x * TW;
    const int ty0 = blockIdx.y * TH;
    const size_t base = (size_t)blockIdx.z * (size_t)(IMG_H * IMG_W);

    // Gaussian weights (match jnp: exp(-d^2/(2*1.5^2)), normalized, f32)
    float g[WIN];
    {
        float s = 0.f;
#pragma unroll
        for (int i = 0; i < WIN; ++i) {
            float d = (float)(i - PAD);
            g[i] = expf(-d * d / 4.5f);
            s += g[i];
        }
        float inv = 1.f / s;
#pragma unroll
        for (int i = 0; i < WIN; ++i) g[i] *= inv;
    }

    // ---- stage: 42 rows x 12 aligned float4 chunks per image ----
    // LDS col L corresponds to global col tx0 - 8 + L. tx0 % 32 == 0, so
    // gc0 = tx0 - 8 + 4k is a multiple of 4 -> 16B-aligned global float4.
    for (int t = tid; t < IH * 12; t += 256) {
        int r = t / 12, k = t - r * 12;
        int gr = ty0 + r - PAD;
        int gc0 = tx0 - 8 + 4 * k;
        float4 a = make_float4(0.f, 0.f, 0.f, 0.f);
        float4 b = make_float4(0.f, 0.f, 0.f, 0.f);
        if (gr >= 0 && gr < IMG_H) {
            const size_t rowoff = base + (size_t)gr * IMG_W;
            if (gc0 >= 0 && gc0 + 3 < IMG_W) {
                a = *(const float4*)(img1 + rowoff + gc0);
                b = *(const float4*)(img2 + rowoff + gc0);
            } else {
                // edge chunk: elementwise with zero fill
                a.x = (gc0 + 0 >= 0 && gc0 + 0 < IMG_W) ? img1[rowoff + gc0 + 0] : 0.f;
                a.y = (gc0 + 1 >= 0 && gc0 + 1 < IMG_W) ? img1[rowoff + gc0 + 1] : 0.f;
                a.z = (gc0 + 2 >= 0 && gc0 + 2 < IMG_W) ? img1[rowoff + gc0 + 2] : 0.f;
                a.w = (gc0 + 3 >= 0 && gc0 + 3 < IMG_W) ? img1[rowoff + gc0 + 3] : 0.f;
                b.x = (gc0 + 0 >= 0 && gc0 + 0 < IMG_W) ? img2[rowoff + gc0 + 0] : 0.f;
                b.y = (gc0 + 1 >= 0 && gc0 + 1 < IMG_W) ? img2[rowoff + gc0 + 1] : 0.f;
                b.z = (gc0 + 2 >= 0 && gc0 + 2 < IMG_W) ? img2[rowoff + gc0 + 2] : 0.f;
                b.w = (gc0 + 3 >= 0 && gc0 + 3 < IMG_W) ? img2[rowoff + gc0 + 3] : 0.f;
            }
        }
        *(float4*)(lx + r * ISTR + 4 * k) = a;
        *(float4*)(ly + r * ISTR + 4 * k) = b;
    }
    __syncthreads();

    // ---- horizontal 11-tap pass: 4 outputs/thread, vector LDS reads ----
    // output col c needs LDS cols c+3 .. c+13; group c0..c0+3 -> c0+3..c0+16,
    // covered by aligned float4 chunks c0 .. c0+19.
    for (int t = tid; t < IH * 8; t += 256) {
        int r = t >> 3, c0 = (t & 7) * 4;
        float ax[20], bx[20];
#pragma unroll
        for (int j = 0; j < 5; ++j) {
            float4 va = *(const float4*)(lx + r * ISTR + c0 + 4 * j);
            float4 vb = *(const float4*)(ly + r * ISTR + c0 + 4 * j);
            ax[4 * j + 0] = va.x; ax[4 * j + 1] = va.y; ax[4 * j + 2] = va.z; ax[4 * j + 3] = va.w;
            bx[4 * j + 0] = vb.x; bx[4 * j + 1] = vb.y; bx[4 * j + 2] = vb.z; bx[4 * j + 3] = vb.w;
        }
#pragma unroll
        for (int cc = 0; cc < 4; ++cc) {
            float sx = 0.f, sy = 0.f, sxx = 0.f, syy = 0.f, sxy = 0.f;
#pragma unroll
            for (int j = 0; j < WIN; ++j) {
                float w = g[j];
                float a = ax[cc + 3 + j];
                float b = bx[cc + 3 + j];
                float wa = w * a, wb = w * b;
                sx += wa;
                sy += wb;
                sxx = fmaf(wa, a, sxx);
                syy = fmaf(wb, b, syy);
                sxy = fmaf(wa, b, sxy);
            }
            h4[r * HSTR + c0 + cc] = make_float4(sx, sy, sxx, syy);
            h1[r * HSTR + c0 + cc] = sxy;
        }
    }
    __syncthreads();

    // ---- vertical 11-tap pass + SSIM map: 4 outputs/thread in a column ----
    const float C2v = 0.0009f;  // (0.03 * 1.0)^2
    float acc = 0.f;
    {
        int c = tid & 31;
        int r0 = (tid >> 5) * 4;           // 8 row-groups x 32 cols = 256 tasks
        float vsx[4] = {0.f, 0.f, 0.f, 0.f};
        float vsy[4] = {0.f, 0.f, 0.f, 0.f};
        float vxx[4] = {0.f, 0.f, 0.f, 0.f};
        float vyy[4] = {0.f, 0.f, 0.f, 0.f};
        float vxy[4] = {0.f, 0.f, 0.f, 0.f};
#pragma unroll
        for (int i = 0; i < WIN + 3; ++i) {
            float4 h = h4[(r0 + i) * HSTR + c];
            float  e = h1[(r0 + i) * HSTR + c];
#pragma unroll
            for (int k = 0; k < 4; ++k) {
                if (i >= k && i <= k + 10) {
                    float w = g[i - k];
                    vsx[k] = fmaf(w, h.x, vsx[k]);
                    vsy[k] = fmaf(w, h.y, vsy[k]);
                    vxx[k] = fmaf(w, h.z, vxx[k]);
                    vyy[k] = fmaf(w, h.w, vyy[k]);
                    vxy[k] = fmaf(w, e,  vxy[k]);
                }
            }
        }
#pragma unroll
        for (int k = 0; k < 4; ++k) {
            float mu12 = vsx[k] * vsy[k];
            float s1 = vxx[k] - vsx[k] * vsx[k];
            float s2 = vyy[k] - vsy[k] * vsy[k];
            float s12 = vxy[k] - mu12;
            float sig = sqrtf(fabsf(s1)) * sqrtf(fabsf(s2));
            acc += (s12 + C2v) / (sig + C2v);
        }
    }

    // ---- block reduction -> one float partial per block (no atomics) ----
#pragma unroll
    for (int off = 32; off > 0; off >>= 1) acc += __shfl_down(acc, off, 64);
    int wave = tid >> 6;
    if ((tid & 63) == 0) wsum[wave] = acc;
    __syncthreads();
    if (tid == 0) {
        int bid = (blockIdx.z * gridDim.y + blockIdx.y) * gridDim.x + blockIdx.x;
        partial[bid] = wsum[0] + wsum[1] + wsum[2] + wsum[3];
    }
}

// ---------------- final reduction ----------------
__global__ __launch_bounds__(256) void ssim_final(const float* __restrict__ partial,
                                                  int n, float* __restrict__ out,
                                                  double inv_total) {
    __shared__ double wsd[4];
    double s = 0.0;
    for (int i = threadIdx.x; i < n; i += 256) s += (double)partial[i];
#pragma unroll
    for (int off = 32; off > 0; off >>= 1) s += __shfl_down(s, off, 64);
    int wave = threadIdx.x >> 6;
    if ((threadIdx.x & 63) == 0) wsd[wave] = s;
    __syncthreads();
    if (threadIdx.x == 0)
        out[0] = (float)((wsd[0] + wsd[1] + wsd[2] + wsd[3]) * inv_total);
}

extern "C" void kernel_launch(void* const* d_in, const int* in_sizes, int n_in,
                              void* d_out, int out_size, void* d_ws, size_t ws_size,
                              hipStream_t stream) {
    const float* img1 = (const float*)d_in[0];
    const float* img2 = (const float*)d_in[1];
    float* out = (float*)d_out;
    float* partial = (float*)d_ws;

    const int total = in_sizes[0];                  // 32*3*512*512
    const int nc = total / (IMG_H * IMG_W);         // 96 images of 512x512

    dim3 grid(IMG_W / TW, IMG_H / TH, nc);          // 16 x 16 x 96 = 24576 blocks
    const int nblocks = grid.x * grid.y * grid.z;

    ssim_main<<<grid, 256, 0, stream>>>(img1, img2, partial);
    ssim_final<<<1, 256, 0, stream>>>(partial, nblocks, out, 1.0 / (double)total);
}

// Round 4
// 302.209 us; speedup vs baseline: 1.5358x; 1.2074x over previous
//
#include <hip/hip_runtime.h>
#include <hip/hip_bf16.h>

#define WIN 11
#define PAD 5
#define TW 32           // tile width (output cols)
#define TH 64           // tile height (output rows)
#define IH 74           // TH + 2*PAD staged rows
#define ISTR 52         // input LDS row stride in floats (13 quads, odd-quad => conflict-free)
#define NCHK 12         // staged float4 chunks per row (48 cols: tx0-8 .. tx0+39)
#define HSTR 33         // h-pass row stride (pixels)
#define IMG_H 512
#define IMG_W 512
#define BLK 512

// ---------------- main fused SSIM kernel ----------------
__global__ __launch_bounds__(BLK, 4) void ssim_main(const float* __restrict__ img1,
                                                    const float* __restrict__ img2,
                                                    float* __restrict__ partial) {
    __shared__ float  lx[IH * ISTR];          // 15392 B
    __shared__ float  ly[IH * ISTR];          // 15392 B
    __shared__ float4 h4[IH * HSTR];          // 39072 B : (sx, sy, sxx, syy)
    __shared__ float  h1[IH * HSTR];          // 9768 B  : sxy
    __shared__ float  wsum[8];

    const int tid = threadIdx.x;
    const int tx0 = blockIdx.x * TW;
    const int ty0 = blockIdx.y * TH;
    const size_t base = (size_t)blockIdx.z * (size_t)(IMG_H * IMG_W);

    // Gaussian weights (match jnp: exp(-d^2/(2*1.5^2)), normalized, f32)
    float g[WIN];
    {
        float s = 0.f;
#pragma unroll
        for (int i = 0; i < WIN; ++i) {
            float d = (float)(i - PAD);
            g[i] = expf(-d * d / 4.5f);
            s += g[i];
        }
        float inv = 1.f / s;
#pragma unroll
        for (int i = 0; i < WIN; ++i) g[i] *= inv;
    }

    // ---- stage: 74 rows x 12 aligned float4 chunks per image ----
    // LDS col L == global col tx0 - 8 + L; gc0 multiple of 4 -> aligned float4.
    const bool interior = (blockIdx.x >= 1) & (blockIdx.x <= 14) &
                          (blockIdx.y >= 1) & (blockIdx.y <= (IMG_H / TH - 2));
    if (interior) {
        for (int t = tid; t < IH * NCHK; t += BLK) {
            int r = t / NCHK, k = t - r * NCHK;
            const size_t off = base + (size_t)(ty0 + r - PAD) * IMG_W + (tx0 - 8 + 4 * k);
            *(float4*)(lx + r * ISTR + 4 * k) = *(const float4*)(img1 + off);
            *(float4*)(ly + r * ISTR + 4 * k) = *(const float4*)(img2 + off);
        }
    } else {
        for (int t = tid; t < IH * NCHK; t += BLK) {
            int r = t / NCHK, k = t - r * NCHK;
            int gr = ty0 + r - PAD;
            int gc0 = tx0 - 8 + 4 * k;
            float4 a = make_float4(0.f, 0.f, 0.f, 0.f);
            float4 b = make_float4(0.f, 0.f, 0.f, 0.f);
            if (gr >= 0 && gr < IMG_H) {
                const size_t rowoff = base + (size_t)gr * IMG_W;
                if (gc0 >= 0 && gc0 + 3 < IMG_W) {
                    a = *(const float4*)(img1 + rowoff + gc0);
                    b = *(const float4*)(img2 + rowoff + gc0);
                } else {
                    a.x = (gc0 + 0 >= 0 && gc0 + 0 < IMG_W) ? img1[rowoff + gc0 + 0] : 0.f;
                    a.y = (gc0 + 1 >= 0 && gc0 + 1 < IMG_W) ? img1[rowoff + gc0 + 1] : 0.f;
                    a.z = (gc0 + 2 >= 0 && gc0 + 2 < IMG_W) ? img1[rowoff + gc0 + 2] : 0.f;
                    a.w = (gc0 + 3 >= 0 && gc0 + 3 < IMG_W) ? img1[rowoff + gc0 + 3] : 0.f;
                    b.x = (gc0 + 0 >= 0 && gc0 + 0 < IMG_W) ? img2[rowoff + gc0 + 0] : 0.f;
                    b.y = (gc0 + 1 >= 0 && gc0 + 1 < IMG_W) ? img2[rowoff + gc0 + 1] : 0.f;
                    b.z = (gc0 + 2 >= 0 && gc0 + 2 < IMG_W) ? img2[rowoff + gc0 + 2] : 0.f;
                    b.w = (gc0 + 3 >= 0 && gc0 + 3 < IMG_W) ? img2[rowoff + gc0 + 3] : 0.f;
                }
            }
            *(float4*)(lx + r * ISTR + 4 * k) = a;
            *(float4*)(ly + r * ISTR + 4 * k) = b;
        }
    }
    __syncthreads();

    // ---- horizontal 11-tap pass: 4 outputs/thread ----
    // Task remap: 8 consecutive lanes -> 8 different rows, same chunk group
    // (makes every LDS read/write <=2-way bank aliased).
    for (int t = tid; t < IH * 8 + 48; t += BLK) {   // 592 tasks padded to loop bound
        int c0g = (t >> 3) & 7;
        int r = (t & 7) + ((t >> 6) << 3);
        if (r < IH) {
            float ax[20], bx[20];
#pragma unroll
            for (int j = 0; j < 5; ++j) {
                float4 va = *(const float4*)(lx + r * ISTR + 4 * (c0g + j));
                float4 vb = *(const float4*)(ly + r * ISTR + 4 * (c0g + j));
                ax[4 * j + 0] = va.x; ax[4 * j + 1] = va.y; ax[4 * j + 2] = va.z; ax[4 * j + 3] = va.w;
                bx[4 * j + 0] = vb.x; bx[4 * j + 1] = vb.y; bx[4 * j + 2] = vb.z; bx[4 * j + 3] = vb.w;
            }
#pragma unroll
            for (int cc = 0; cc < 4; ++cc) {
                float sx = 0.f, sy = 0.f, sxx = 0.f, syy = 0.f, sxy = 0.f;
#pragma unroll
                for (int j = 0; j < WIN; ++j) {
                    float w = g[j];
                    float a = ax[cc + 3 + j];
                    float b = bx[cc + 3 + j];
                    float wa = w * a, wb = w * b;
                    sx += wa;
                    sy += wb;
                    sxx = fmaf(wa, a, sxx);
                    syy = fmaf(wb, b, syy);
                    sxy = fmaf(wa, b, sxy);
                }
                int o = r * HSTR + 4 * c0g + cc;
                h4[o] = make_float4(sx, sy, sxx, syy);
                h1[o] = sxy;
            }
        }
    }
    __syncthreads();

    // ---- vertical 11-tap pass + SSIM map: 4 outputs/thread in a column ----
    const float C2v = 0.0009f;  // (0.03 * 1.0)^2
    float acc = 0.f;
    {
        int c = tid & 31;
        int r0 = (tid >> 5) * 4;           // 16 row-groups x 32 cols = 512 tasks
        float vsx[4] = {0.f, 0.f, 0.f, 0.f};
        float vsy[4] = {0.f, 0.f, 0.f, 0.f};
        float vxx[4] = {0.f, 0.f, 0.f, 0.f};
        float vyy[4] = {0.f, 0.f, 0.f, 0.f};
        float vxy[4] = {0.f, 0.f, 0.f, 0.f};
#pragma unroll
        for (int i = 0; i < WIN + 3; ++i) {
            float4 h = h4[(r0 + i) * HSTR + c];
            float  e = h1[(r0 + i) * HSTR + c];
#pragma unroll
            for (int k = 0; k < 4; ++k) {
                if (i >= k && i <= k + 10) {
                    float w = g[i - k];
                    vsx[k] = fmaf(w, h.x, vsx[k]);
                    vsy[k] = fmaf(w, h.y, vsy[k]);
                    vxx[k] = fmaf(w, h.z, vxx[k]);
                    vyy[k] = fmaf(w, h.w, vyy[k]);
                    vxy[k] = fmaf(w, e,  vxy[k]);
                }
            }
        }
#pragma unroll
        for (int k = 0; k < 4; ++k) {
            float mu12 = vsx[k] * vsy[k];
            float s1 = vxx[k] - vsx[k] * vsx[k];
            float s2 = vyy[k] - vsy[k] * vsy[k];
            float s12 = vxy[k] - mu12;
            float sig = sqrtf(fabsf(s1)) * sqrtf(fabsf(s2));
            acc += (s12 + C2v) / (sig + C2v);
        }
    }

    // ---- block reduction -> one float partial per block ----
#pragma unroll
    for (int off = 32; off > 0; off >>= 1) acc += __shfl_down(acc, off, 64);
    int wave = tid >> 6;
    if ((tid & 63) == 0) wsum[wave] = acc;
    __syncthreads();
    if (tid == 0) {
        float b = 0.f;
#pragma unroll
        for (int w = 0; w < BLK / 64; ++w) b += wsum[w];
        int bid = (blockIdx.z * gridDim.y + blockIdx.y) * gridDim.x + blockIdx.x;
        partial[bid] = b;
    }
}

// ---------------- final reduction ----------------
__global__ __launch_bounds__(1024) void ssim_final(const float* __restrict__ partial,
                                                   int n, float* __restrict__ out,
                                                   double inv_total) {
    __shared__ double wsd[16];
    double s = 0.0;
    const float4* p4 = (const float4*)partial;
    for (int i = threadIdx.x; i < n / 4; i += 1024) {
        float4 v = p4[i];
        s += (double)v.x + (double)v.y + (double)v.z + (double)v.w;
    }
#pragma unroll
    for (int off = 32; off > 0; off >>= 1) s += __shfl_down(s, off, 64);
    int wave = threadIdx.x >> 6;
    if ((threadIdx.x & 63) == 0) wsd[wave] = s;
    __syncthreads();
    if (threadIdx.x == 0) {
        double t = 0.0;
#pragma unroll
        for (int w = 0; w < 16; ++w) t += wsd[w];
        out[0] = (float)(t * inv_total);
    }
}

extern "C" void kernel_launch(void* const* d_in, const int* in_sizes, int n_in,
                              void* d_out, int out_size, void* d_ws, size_t ws_size,
                              hipStream_t stream) {
    const float* img1 = (const float*)d_in[0];
    const float* img2 = (const float*)d_in[1];
    float* out = (float*)d_out;
    float* partial = (float*)d_ws;

    const int total = in_sizes[0];                  // 32*3*512*512
    const int nc = total / (IMG_H * IMG_W);         // 96 images of 512x512

    dim3 grid(IMG_W / TW, IMG_H / TH, nc);          // 16 x 8 x 96 = 12288 blocks
    const int nblocks = grid.x * grid.y * grid.z;   // divisible by 4

    ssim_main<<<grid, BLK, 0, stream>>>(img1, img2, partial);
    ssim_final<<<1, 1024, 0, stream>>>(partial, nblocks, out, 1.0 / (double)total);
}